// Round 4
// baseline (790.865 us; speedup 1.0000x reference)
//
#include <hip/hip_runtime.h>
#include <math.h>

#define N0 1048576
#define N1 65536
#define N2 4096
#define DEG0 16
#define DEG1 10
#define D_IN 128
#define D_H 256
#define D_OUT 47

typedef unsigned int uint32;
typedef __attribute__((ext_vector_type(8))) short bf16x8;
typedef __attribute__((ext_vector_type(4))) float f32x4;

__device__ __forceinline__ unsigned short f2b(float x) {
    // fp32 -> bf16 round-to-nearest-even (no NaN inputs in this workload)
    uint32 u = __float_as_uint(x);
    return (unsigned short)((u + 0x7fffu + ((u >> 16) & 1u)) >> 16);
}
__device__ __forceinline__ float b2f(unsigned short h) {
    return __uint_as_float(((uint32)h) << 16);
}
__device__ __forceinline__ float gelu_exact(float x) {
    return 0.5f * x * (1.0f + erff(x * 0.70710678118654752f));
}
__device__ __forceinline__ void split4(const float4 v, ushort4& h, ushort4& l) {
    h.x = f2b(v.x); l.x = f2b(v.x - b2f(h.x));
    h.y = f2b(v.y); l.y = f2b(v.y - b2f(h.y));
    h.z = f2b(v.z); l.z = f2b(v.z - b2f(h.z));
    h.w = f2b(v.w); l.w = f2b(v.w - b2f(h.w));
}

// ---------------------------------------------------------------------------
// Minimal prep: split only Wl0/Wr0 (l0_fused's hot-loop B operands) to planes.
// L1/final GEMMs split their weights during LDS staging instead (they are
// latency-bound small kernels with VALU slack; l0 is not).
// ---------------------------------------------------------------------------
__global__ __launch_bounds__(256) void prep_w0(
    const float4* __restrict__ Wl0, const float4* __restrict__ Wr0,
    ushort4* __restrict__ wl0h, ushort4* __restrict__ wl0l,
    ushort4* __restrict__ wr0h, ushort4* __restrict__ wr0l)
{
    int i = blockIdx.x * 256 + threadIdx.x;   // 16384 quads total
    const float4* src; ushort4 *dh, *dl;
    if (i < 8192) { src = Wl0 + i; dh = wl0h + i; dl = wl0l + i; }
    else          { int r = i - 8192; src = Wr0 + r; dh = wr0h + r; dl = wr0l + r; }
    float4 v = *src;
    ushort4 h, l; split4(v, h, l);
    *dh = h; *dl = l;
}

// ---------------------------------------------------------------------------
// Mean aggregation, hi/lo bf16 planes in -> hi/lo bf16 planes out (layer 1).
// ---------------------------------------------------------------------------
template <int DEG, int F4>
__global__ __launch_bounds__(256) void agg_split_bf16(
    const ushort4* __restrict__ fh, const ushort4* __restrict__ fl,
    const int* __restrict__ idx,
    ushort4* __restrict__ oh, ushort4* __restrict__ ol, int ndst)
{
    const int lane  = threadIdx.x % F4;
    const int local = threadIdx.x / F4;
    const int j = blockIdx.x * (256 / F4) + local;
    if (j >= ndst) return;

    const int* ip = idx + (long)j * DEG;
    int srcs[DEG];
#pragma unroll
    for (int e = 0; e < DEG; ++e) srcs[e] = ip[e];

    float4 acc = make_float4(0.f, 0.f, 0.f, 0.f);
#pragma unroll
    for (int e = 0; e < DEG; ++e) {
        long o = (long)srcs[e] * F4 + lane;
        ushort4 h = fh[o], l = fl[o];
        acc.x += b2f(h.x) + b2f(l.x);
        acc.y += b2f(h.y) + b2f(l.y);
        acc.z += b2f(h.z) + b2f(l.z);
        acc.w += b2f(h.w) + b2f(l.w);
    }
    const float r = 1.0f / (float)DEG;
    acc.x *= r; acc.y *= r; acc.z *= r; acc.w *= r;
    ushort4 h, l; split4(acc, h, l);
    oh[(long)j * F4 + lane] = h;
    ol[(long)j * F4 + lane] = l;
}

// ---------------------------------------------------------------------------
// Split-bf16 MFMA GEMM (layers 1 and output): C = act([A1|A2] @ [B1|B2]^T + b)
// A operands are hi/lo bf16 plane pairs; B operands are fp32 weights, with the
// hi/lo split fused into LDS staging (same bytes as plane pairs: 4 = 2+2).
// Rows of B beyond nrowsB are staged as zero (Wo 47 -> 64 padding).
// Tile BM=128, BN=64, BK=32; 4 waves; layouts verified (learn_hip m89/m120).
// ---------------------------------------------------------------------------
template <int K1, int K2, bool GELU, bool SPLIT_OUT>
__global__ __launch_bounds__(256) void gemm_mfma(
    const unsigned short* __restrict__ A1h, const unsigned short* __restrict__ A1l,
    const unsigned short* __restrict__ A2h, const unsigned short* __restrict__ A2l,
    const float* __restrict__ B1f, const float* __restrict__ B2f, int nrowsB,
    const float* __restrict__ bias,
    float* __restrict__ Cf, unsigned short* __restrict__ Ch, unsigned short* __restrict__ Cl,
    int ldc, int ncols)
{
    constexpr int BK = 32, LDK = 40;  // +8 pad: row stride 80B breaks conflicts
    __shared__ unsigned short sA[2][128][LDK];
    __shared__ unsigned short sB[2][64][LDK];

    const int tid  = threadIdx.x;
    const int bm   = blockIdx.x, bn = blockIdx.y;
    const int w    = tid >> 6;
    const int lane = tid & 63;
    const int quad = lane >> 4;
    const int l16  = lane & 15;

    f32x4 acc[2][4];
#pragma unroll
    for (int mt = 0; mt < 2; ++mt)
#pragma unroll
        for (int nt = 0; nt < 4; ++nt) acc[mt][nt] = (f32x4)0.f;

    constexpr int KT = (K1 + K2) / BK;
    for (int kt = 0; kt < KT; ++kt) {
        const int k0 = kt * BK;
        const unsigned short *Ah, *Al;
        const float* Bf;
        int ka, koff;
        if (k0 < K1) { Ah = A1h; Al = A1l; Bf = B1f; ka = K1; koff = k0; }
        else         { Ah = A2h; Al = A2l; Bf = B2f; ka = (K2 ? K2 : 1); koff = k0 - K1; }

        // stage A: 128 rows x 32 k (per plane) as 512 x 16B tasks
#pragma unroll
        for (int rep = 0; rep < 2; ++rep) {
            int task = tid + rep * 256;
            int row = task >> 2, seg = task & 3;
            size_t g = (size_t)(bm * 128 + row) * ka + koff + seg * 8;
            *(uint4*)&sA[0][row][seg * 8] = *(const uint4*)(Ah + g);
            *(uint4*)&sA[1][row][seg * 8] = *(const uint4*)(Al + g);
        }
        // stage B: 64 rows x 32 k from fp32, split fused (zero-pad rows >= nrowsB)
        {
            int row = tid >> 2, seg = tid & 3;
            int brow = bn * 64 + row;
            float4 f0 = make_float4(0.f, 0.f, 0.f, 0.f), f1 = f0;
            if (brow < nrowsB) {
                const float* src = Bf + (size_t)brow * ka + koff + seg * 8;
                f0 = *(const float4*)src;
                f1 = *(const float4*)(src + 4);
            }
            ushort4 bh0, bl0, bh1, bl1;
            split4(f0, bh0, bl0); split4(f1, bh1, bl1);
            *(ushort4*)&sB[0][row][seg * 8]     = bh0;
            *(ushort4*)&sB[0][row][seg * 8 + 4] = bh1;
            *(ushort4*)&sB[1][row][seg * 8]     = bl0;
            *(ushort4*)&sB[1][row][seg * 8 + 4] = bl1;
        }
        __syncthreads();

        bf16x8 Afh[2], Afl[2], Bfh[4], Bfl[4];
#pragma unroll
        for (int mt = 0; mt < 2; ++mt) {
            int r = w * 32 + mt * 16 + l16;
            Afh[mt] = *(const bf16x8*)&sA[0][r][quad * 8];
            Afl[mt] = *(const bf16x8*)&sA[1][r][quad * 8];
        }
#pragma unroll
        for (int nt = 0; nt < 4; ++nt) {
            int r = nt * 16 + l16;
            Bfh[nt] = *(const bf16x8*)&sB[0][r][quad * 8];
            Bfl[nt] = *(const bf16x8*)&sB[1][r][quad * 8];
        }
#pragma unroll
        for (int mt = 0; mt < 2; ++mt)
#pragma unroll
            for (int nt = 0; nt < 4; ++nt) {
                acc[mt][nt] = __builtin_amdgcn_mfma_f32_16x16x32_bf16(
                    Afl[mt], Bfh[nt], acc[mt][nt], 0, 0, 0);
                acc[mt][nt] = __builtin_amdgcn_mfma_f32_16x16x32_bf16(
                    Afh[mt], Bfl[nt], acc[mt][nt], 0, 0, 0);
                acc[mt][nt] = __builtin_amdgcn_mfma_f32_16x16x32_bf16(
                    Afh[mt], Bfh[nt], acc[mt][nt], 0, 0, 0);
            }
        __syncthreads();
    }

#pragma unroll
    for (int mt = 0; mt < 2; ++mt) {
        const int row0 = bm * 128 + w * 32 + mt * 16 + quad * 4;
#pragma unroll
        for (int nt = 0; nt < 4; ++nt) {
            const int col = bn * 64 + nt * 16 + l16;
            const float bb = (col < ncols) ? bias[col] : 0.f;
#pragma unroll
            for (int r = 0; r < 4; ++r) {
                float v = acc[mt][nt][r] + bb;
                if (GELU) v = gelu_exact(v);
                if (SPLIT_OUT) {
                    unsigned short h = f2b(v);
                    Ch[(size_t)(row0 + r) * ldc + col] = h;
                    Cl[(size_t)(row0 + r) * ldc + col] = f2b(v - b2f(h));
                } else {
                    if (col < ncols) Cf[(size_t)(row0 + r) * ldc + col] = v;
                }
            }
        }
    }
}

// ---------------------------------------------------------------------------
// FUSED layer 0 (round-1 proven structure, BM=128, grid=512): gather(x)+mean
// -> registers (hi/lo bf16), then split-bf16 MFMA GEMM over all 256 output
// cols (bn loop), A2 staged straight from fp32 x, B from PRE-SPLIT planes
// (pure loads + ds_write in the hot phase -- no split VALU between barriers;
// fp32-split staging here measurably regressed, round 3).
// ---------------------------------------------------------------------------
__global__ __launch_bounds__(256) void l0_fused(
    const float4* __restrict__ x4, const int* __restrict__ idx0,
    const unsigned short* __restrict__ B1h, const unsigned short* __restrict__ B1l,
    const unsigned short* __restrict__ B2h, const unsigned short* __restrict__ B2l,
    const float* __restrict__ bias,
    unsigned short* __restrict__ Ch, unsigned short* __restrict__ Cl)
{
    constexpr int LDK = 40;
    __shared__ int sIdx[128 * DEG0];            // 8 KB
    __shared__ unsigned short sA[2][128][LDK];  // 20.5 KB
    __shared__ unsigned short sB[2][64][LDK];   // 10.25 KB

    const int tid  = threadIdx.x;
    const int bm   = blockIdx.x;
    const int w    = tid >> 6;
    const int l64  = tid & 63;
    const int quad = l64 >> 4;
    const int l16  = l64 & 15;
    const int lane = tid & 31;   // gather lane (32 lanes cover one 512B row)
    const int grp  = tid >> 5;   // gather group 0..7, owns rows grp*16..+15

    // stage this block's 2048 edge indices (coalesced int4)
    {
        const int4* s = (const int4*)(idx0 + (size_t)bm * (128 * DEG0));
        int4* d = (int4*)sIdx;
        d[tid]       = s[tid];
        d[tid + 256] = s[tid + 256];
    }
    __syncthreads();

    // phase 1: gather + mean; thread owns rows grp*16+i, cols lane*4..+3.
    // Result split to hi/lo bf16 kept in registers (64 VGPRs).
    ushort4 ah[16], al[16];
#pragma unroll
    for (int i = 0; i < 16; ++i) {
        const int rb = (grp * 16 + i) * DEG0;
        float4 a = make_float4(0.f, 0.f, 0.f, 0.f);
#pragma unroll
        for (int e = 0; e < DEG0; ++e) {
            const float4 v = x4[(size_t)sIdx[rb + e] * (D_IN / 4) + lane];
            a.x += v.x; a.y += v.y; a.z += v.z; a.w += v.w;
        }
        const float r = 1.0f / (float)DEG0;
        a.x *= r; a.y *= r; a.z *= r; a.w *= r;
        split4(a, ah[i], al[i]);
    }

    const int arow  = tid >> 1;  // A2 staging: 2 threads per row
    const int ahalf = tid & 1;

    for (int bn = 0; bn < 4; ++bn) {
        f32x4 acc[2][4];
#pragma unroll
        for (int mt = 0; mt < 2; ++mt)
#pragma unroll
            for (int nt = 0; nt < 4; ++nt) acc[mt][nt] = (f32x4)0.f;

#pragma unroll
        for (int kt = 0; kt < 8; ++kt) {
            const int k0 = kt * 32;
            // ---- stage A k-tile ----
            if (kt < 4) {
                // A1 (aggregated mean) from registers: cols kt*32..+31 live in
                // lanes with (lane>>3)==kt; each writes its 16 rows x 4 cols.
                if ((lane >> 3) == kt) {
                    const int c = (lane & 7) * 4;
#pragma unroll
                    for (int i = 0; i < 16; ++i) {
                        const int rr = grp * 16 + i;
                        *(ushort4*)&sA[0][rr][c] = ah[i];
                        *(ushort4*)&sA[1][rr][c] = al[i];
                    }
                }
            } else {
                // A2 = x[dst] fp32, convert during staging (L2-hot after bn=0)
                const float4* sx = x4 + (size_t)(bm * 128 + arow) * (D_IN / 4)
                                      + (kt - 4) * 8 + ahalf * 4;
#pragma unroll
                for (int q = 0; q < 4; ++q) {
                    ushort4 h, l;
                    split4(sx[q], h, l);
                    const int c = ahalf * 16 + q * 4;
                    *(ushort4*)&sA[0][arow][c] = h;
                    *(ushort4*)&sA[1][arow][c] = l;
                }
            }
            // ---- stage B k-tile from pre-split planes (L2-resident) ----
            {
                const int row = tid >> 2, seg = tid & 3;
                const unsigned short *Bh, *Bl; int koff;
                if (k0 < D_IN) { Bh = B1h; Bl = B1l; koff = k0; }
                else           { Bh = B2h; Bl = B2l; koff = k0 - D_IN; }
                const size_t g = (size_t)(bn * 64 + row) * D_IN + koff + seg * 8;
                *(uint4*)&sB[0][row][seg * 8] = *(const uint4*)(Bh + g);
                *(uint4*)&sB[1][row][seg * 8] = *(const uint4*)(Bl + g);
            }
            __syncthreads();

            bf16x8 Afh[2], Afl[2];
#pragma unroll
            for (int mt = 0; mt < 2; ++mt) {
                const int r = w * 32 + mt * 16 + l16;
                Afh[mt] = *(const bf16x8*)&sA[0][r][quad * 8];
                Afl[mt] = *(const bf16x8*)&sA[1][r][quad * 8];
            }
#pragma unroll
            for (int nt = 0; nt < 4; ++nt) {
                const int r = nt * 16 + l16;
                const bf16x8 Bfh = *(const bf16x8*)&sB[0][r][quad * 8];
                const bf16x8 Bfl = *(const bf16x8*)&sB[1][r][quad * 8];
#pragma unroll
                for (int mt = 0; mt < 2; ++mt) {
                    acc[mt][nt] = __builtin_amdgcn_mfma_f32_16x16x32_bf16(
                        Afl[mt], Bfh, acc[mt][nt], 0, 0, 0);
                    acc[mt][nt] = __builtin_amdgcn_mfma_f32_16x16x32_bf16(
                        Afh[mt], Bfl, acc[mt][nt], 0, 0, 0);
                    acc[mt][nt] = __builtin_amdgcn_mfma_f32_16x16x32_bf16(
                        Afh[mt], Bfh, acc[mt][nt], 0, 0, 0);
                }
            }
            __syncthreads();
        }

        // epilogue for this bn: D layout col=lane&15, row=quad*4+reg
#pragma unroll
        for (int mt = 0; mt < 2; ++mt) {
            const int row0 = bm * 128 + w * 32 + mt * 16 + quad * 4;
#pragma unroll
            for (int nt = 0; nt < 4; ++nt) {
                const int col = bn * 64 + nt * 16 + l16;
                const float bb = bias[col];
#pragma unroll
                for (int r = 0; r < 4; ++r) {
                    float v = gelu_exact(acc[mt][nt][r] + bb);
                    const unsigned short h = f2b(v);
                    Ch[(size_t)(row0 + r) * D_H + col] = h;
                    Cl[(size_t)(row0 + r) * D_H + col] = f2b(v - b2f(h));
                }
            }
        }
    }
}

extern "C" void kernel_launch(void* const* d_in, const int* in_sizes, int n_in,
                              void* d_out, int out_size, void* d_ws, size_t ws_size,
                              hipStream_t stream)
{
    const float* x        = (const float*)d_in[0];
    const int*   indices0 = (const int*)d_in[1];
    const int*   indices1 = (const int*)d_in[3];
    const float* Wl0 = (const float*)d_in[5];
    const float* bl0 = (const float*)d_in[6];
    const float* Wr0 = (const float*)d_in[7];
    const float* Wl1 = (const float*)d_in[8];
    const float* bl1 = (const float*)d_in[9];
    const float* Wr1 = (const float*)d_in[10];
    const float* Wo  = (const float*)d_in[11];
    const float* bo  = (const float*)d_in[12];
    float* out = (float*)d_out;

    // Workspace: hi/lo bf16 planes (ushort)
    unsigned short* p = (unsigned short*)d_ws;
    unsigned short* h0h  = p; p += (size_t)N1 * D_H;
    unsigned short* h0l  = p; p += (size_t)N1 * D_H;
    unsigned short* m1h  = p; p += (size_t)N2 * D_H;
    unsigned short* m1l  = p; p += (size_t)N2 * D_H;
    unsigned short* h1h  = p; p += (size_t)N2 * D_H;
    unsigned short* h1l  = p; p += (size_t)N2 * D_H;
    unsigned short* wl0h = p; p += 256 * 128;
    unsigned short* wl0l = p; p += 256 * 128;
    unsigned short* wr0h = p; p += 256 * 128;
    unsigned short* wr0l = p; p += 256 * 128;

    // --- minimal prep: only the l0 weight planes ---
    prep_w0<<<64, 256, 0, stream>>>(
        (const float4*)Wl0, (const float4*)Wr0,
        (ushort4*)wl0h, (ushort4*)wl0l, (ushort4*)wr0h, (ushort4*)wr0l);

    // --- layer 0: fused gather + mean + GEMM + GELU (plane B) ---
    l0_fused<<<N1 / 128, 256, 0, stream>>>(
        (const float4*)x, indices0, wl0h, wl0l, wr0h, wr0l, bl0, h0h, h0l);

    // --- layer 1 aggregation ---
    agg_split_bf16<DEG1, D_H / 4><<<N2 / (256 / (D_H / 4)), 256, 0, stream>>>(
        (const ushort4*)h0h, (const ushort4*)h0l, indices1, (ushort4*)m1h, (ushort4*)m1l, N2);

    // --- layer 1 GEMM (weights split during staging) ---
    gemm_mfma<D_H, D_H, true, true><<<dim3(N2 / 128, D_H / 64), 256, 0, stream>>>(
        m1h, m1l, h0h, h0l, Wl1, Wr1, D_H, bl1,
        nullptr, h1h, h1l, D_H, D_H);

    // --- final projection: B rows zero-padded 47->64 in staging ---
    gemm_mfma<D_H, 0, false, false><<<dim3(N2 / 128, 1), 256, 0, stream>>>(
        h1h, h1l, h1h, h1l, Wo, Wo, D_OUT, bo,
        out, nullptr, nullptr, D_OUT, D_OUT);
}

// Round 6
// 771.932 us; speedup vs baseline: 1.0245x; 1.0245x over previous
//
#include <hip/hip_runtime.h>
#include <math.h>

#define N0 1048576
#define N1 65536
#define N2 4096
#define DEG0 16
#define DEG1 10
#define D_IN 128
#define D_H 256
#define D_OUT 47

typedef unsigned int uint32;
typedef __attribute__((ext_vector_type(8))) short bf16x8;
typedef __attribute__((ext_vector_type(4))) float f32x4;

__device__ __forceinline__ unsigned short f2b(float x) {
    // fp32 -> bf16 round-to-nearest-even (no NaN inputs in this workload)
    uint32 u = __float_as_uint(x);
    return (unsigned short)((u + 0x7fffu + ((u >> 16) & 1u)) >> 16);
}
__device__ __forceinline__ float b2f(unsigned short h) {
    return __uint_as_float(((uint32)h) << 16);
}
__device__ __forceinline__ float gelu_exact(float x) {
    return 0.5f * x * (1.0f + erff(x * 0.70710678118654752f));
}
__device__ __forceinline__ void split4(const float4 v, ushort4& h, ushort4& l) {
    h.x = f2b(v.x); l.x = f2b(v.x - b2f(h.x));
    h.y = f2b(v.y); l.y = f2b(v.y - b2f(h.y));
    h.z = f2b(v.z); l.z = f2b(v.z - b2f(h.z));
    h.w = f2b(v.w); l.w = f2b(v.w - b2f(h.w));
}

// ---------------------------------------------------------------------------
// All weight conversions in ONE launch.
// Segments (float4 quads): Wl0 8192 | Wr0 8192 | Wl1 16384 | Wr1 16384 | Wo 4096
// ---------------------------------------------------------------------------
__global__ __launch_bounds__(256) void prep_all(
    const float4* __restrict__ Wl0, const float4* __restrict__ Wr0,
    const float4* __restrict__ Wl1, const float4* __restrict__ Wr1,
    const float4* __restrict__ Wo,  const float* __restrict__ bo,
    ushort4* __restrict__ wl0h, ushort4* __restrict__ wl0l,
    ushort4* __restrict__ wr0h, ushort4* __restrict__ wr0l,
    ushort4* __restrict__ wl1h, ushort4* __restrict__ wl1l,
    ushort4* __restrict__ wr1h, ushort4* __restrict__ wr1l,
    ushort4* __restrict__ woh,  ushort4* __restrict__ wol,
    float* __restrict__ bo_pad)
{
    int i = blockIdx.x * 256 + threadIdx.x;
    if (i >= 53248) return;
    const float4* src; ushort4 *dh, *dl; int rel;
    if (i < 8192)       { rel = i;         src = Wl0 + rel; dh = wl0h + rel; dl = wl0l + rel; }
    else if (i < 16384) { rel = i - 8192;  src = Wr0 + rel; dh = wr0h + rel; dl = wr0l + rel; }
    else if (i < 32768) { rel = i - 16384; src = Wl1 + rel; dh = wl1h + rel; dl = wl1l + rel; }
    else if (i < 49152) { rel = i - 32768; src = Wr1 + rel; dh = wr1h + rel; dl = wr1l + rel; }
    else {
        // Wo (47x256) -> zero-padded 64x256 planes; bo -> padded 64 floats
        rel = i - 49152;
        float4 v = make_float4(0.f, 0.f, 0.f, 0.f);
        if (((rel * 4) >> 8) < D_OUT) v = Wo[rel];
        ushort4 h, l; split4(v, h, l);
        woh[rel] = h; wol[rel] = l;
        if (rel < 64) bo_pad[rel] = (rel < D_OUT) ? bo[rel] : 0.f;
        return;
    }
    float4 v = *src;
    ushort4 h, l; split4(v, h, l);
    *dh = h; *dl = l;
}

// ---------------------------------------------------------------------------
// Mean aggregation, hi/lo bf16 planes in -> hi/lo bf16 planes out (layer 1).
// ---------------------------------------------------------------------------
template <int DEG, int F4>
__global__ __launch_bounds__(256) void agg_split_bf16(
    const ushort4* __restrict__ fh, const ushort4* __restrict__ fl,
    const int* __restrict__ idx,
    ushort4* __restrict__ oh, ushort4* __restrict__ ol, int ndst)
{
    const int lane  = threadIdx.x % F4;
    const int local = threadIdx.x / F4;
    const int j = blockIdx.x * (256 / F4) + local;
    if (j >= ndst) return;

    const int* ip = idx + (long)j * DEG;
    int srcs[DEG];
#pragma unroll
    for (int e = 0; e < DEG; ++e) srcs[e] = ip[e];

    float4 acc = make_float4(0.f, 0.f, 0.f, 0.f);
#pragma unroll
    for (int e = 0; e < DEG; ++e) {
        long o = (long)srcs[e] * F4 + lane;
        ushort4 h = fh[o], l = fl[o];
        acc.x += b2f(h.x) + b2f(l.x);
        acc.y += b2f(h.y) + b2f(l.y);
        acc.z += b2f(h.z) + b2f(l.z);
        acc.w += b2f(h.w) + b2f(l.w);
    }
    const float r = 1.0f / (float)DEG;
    acc.x *= r; acc.y *= r; acc.z *= r; acc.w *= r;
    ushort4 h, l; split4(acc, h, l);
    oh[(long)j * F4 + lane] = h;
    ol[(long)j * F4 + lane] = l;
}

// ---------------------------------------------------------------------------
// Split-bf16 MFMA GEMM (layers 1 and output): C = act([A1|A2] @ [B1|B2]^T + b)
// Tile BM=128, BN=64, BK=32; 4 waves; layouts verified (learn_hip m89/m120).
// ---------------------------------------------------------------------------
template <int K1, int K2, bool GELU, bool SPLIT_OUT>
__global__ __launch_bounds__(256) void gemm_mfma(
    const unsigned short* __restrict__ A1h, const unsigned short* __restrict__ A1l,
    const unsigned short* __restrict__ A2h, const unsigned short* __restrict__ A2l,
    const unsigned short* __restrict__ B1h, const unsigned short* __restrict__ B1l,
    const unsigned short* __restrict__ B2h, const unsigned short* __restrict__ B2l,
    const float* __restrict__ bias,
    float* __restrict__ Cf, unsigned short* __restrict__ Ch, unsigned short* __restrict__ Cl,
    int ldc, int ncols)
{
    constexpr int BK = 32, LDK = 40;  // +8 pad: row stride 80B breaks conflicts
    __shared__ unsigned short sA[2][128][LDK];
    __shared__ unsigned short sB[2][64][LDK];

    const int tid  = threadIdx.x;
    const int bm   = blockIdx.x, bn = blockIdx.y;
    const int w    = tid >> 6;
    const int lane = tid & 63;
    const int quad = lane >> 4;
    const int l16  = lane & 15;

    f32x4 acc[2][4];
#pragma unroll
    for (int mt = 0; mt < 2; ++mt)
#pragma unroll
        for (int nt = 0; nt < 4; ++nt) acc[mt][nt] = (f32x4)0.f;

    constexpr int KT = (K1 + K2) / BK;
    for (int kt = 0; kt < KT; ++kt) {
        const int k0 = kt * BK;
        const unsigned short *Ah, *Al, *Bh, *Bl;
        int ka, koff;
        if (k0 < K1) { Ah = A1h; Al = A1l; Bh = B1h; Bl = B1l; ka = K1; koff = k0; }
        else         { Ah = A2h; Al = A2l; Bh = B2h; Bl = B2l; ka = (K2 ? K2 : 1); koff = k0 - K1; }

#pragma unroll
        for (int rep = 0; rep < 2; ++rep) {
            int task = tid + rep * 256;
            int row = task >> 2, seg = task & 3;
            size_t g = (size_t)(bm * 128 + row) * ka + koff + seg * 8;
            *(uint4*)&sA[0][row][seg * 8] = *(const uint4*)(Ah + g);
            *(uint4*)&sA[1][row][seg * 8] = *(const uint4*)(Al + g);
        }
        {
            int row = tid >> 2, seg = tid & 3;
            size_t g = (size_t)(bn * 64 + row) * ka + koff + seg * 8;
            *(uint4*)&sB[0][row][seg * 8] = *(const uint4*)(Bh + g);
            *(uint4*)&sB[1][row][seg * 8] = *(const uint4*)(Bl + g);
        }
        __syncthreads();

        bf16x8 Afh[2], Afl[2], Bfh[4], Bfl[4];
#pragma unroll
        for (int mt = 0; mt < 2; ++mt) {
            int r = w * 32 + mt * 16 + l16;
            Afh[mt] = *(const bf16x8*)&sA[0][r][quad * 8];
            Afl[mt] = *(const bf16x8*)&sA[1][r][quad * 8];
        }
#pragma unroll
        for (int nt = 0; nt < 4; ++nt) {
            int r = nt * 16 + l16;
            Bfh[nt] = *(const bf16x8*)&sB[0][r][quad * 8];
            Bfl[nt] = *(const bf16x8*)&sB[1][r][quad * 8];
        }
#pragma unroll
        for (int mt = 0; mt < 2; ++mt)
#pragma unroll
            for (int nt = 0; nt < 4; ++nt) {
                acc[mt][nt] = __builtin_amdgcn_mfma_f32_16x16x32_bf16(
                    Afl[mt], Bfh[nt], acc[mt][nt], 0, 0, 0);
                acc[mt][nt] = __builtin_amdgcn_mfma_f32_16x16x32_bf16(
                    Afh[mt], Bfl[nt], acc[mt][nt], 0, 0, 0);
                acc[mt][nt] = __builtin_amdgcn_mfma_f32_16x16x32_bf16(
                    Afh[mt], Bfh[nt], acc[mt][nt], 0, 0, 0);
            }
        __syncthreads();
    }

#pragma unroll
    for (int mt = 0; mt < 2; ++mt) {
        const int row0 = bm * 128 + w * 32 + mt * 16 + quad * 4;
#pragma unroll
        for (int nt = 0; nt < 4; ++nt) {
            const int col = bn * 64 + nt * 16 + l16;
            const float bb = bias[col];
#pragma unroll
            for (int r = 0; r < 4; ++r) {
                float v = acc[mt][nt][r] + bb;
                if (GELU) v = gelu_exact(v);
                if (SPLIT_OUT) {
                    unsigned short h = f2b(v);
                    Ch[(size_t)(row0 + r) * ldc + col] = h;
                    Cl[(size_t)(row0 + r) * ldc + col] = f2b(v - b2f(h));
                } else {
                    if (col < ncols) Cf[(size_t)(row0 + r) * ldc + col] = v;
                }
            }
        }
    }
}

// ---------------------------------------------------------------------------
// FUSED layer 0: gather(x)+mean -> registers (hi/lo bf16), then the 128-row
// split-bf16 MFMA GEMM over all 256 output cols (bn loop), A2 staged straight
// from fp32 x (conversion fused into staging). Measured-best configuration
// (round 1, 772.8 us): BM=128, grid=512, plane-B staging (pure loads in the
// hot phase). BM=64/grid-1024 (r2) and fp32-split B staging (r3/r4) both
// measured worse.
// ---------------------------------------------------------------------------
__global__ __launch_bounds__(256) void l0_fused(
    const float4* __restrict__ x4, const int* __restrict__ idx0,
    const unsigned short* __restrict__ B1h, const unsigned short* __restrict__ B1l,
    const unsigned short* __restrict__ B2h, const unsigned short* __restrict__ B2l,
    const float* __restrict__ bias,
    unsigned short* __restrict__ Ch, unsigned short* __restrict__ Cl)
{
    constexpr int LDK = 40;
    __shared__ int sIdx[128 * DEG0];            // 8 KB
    __shared__ unsigned short sA[2][128][LDK];  // 20.5 KB
    __shared__ unsigned short sB[2][64][LDK];   // 10.25 KB

    const int tid  = threadIdx.x;
    const int bm   = blockIdx.x;
    const int w    = tid >> 6;
    const int l64  = tid & 63;
    const int quad = l64 >> 4;
    const int l16  = l64 & 15;
    const int lane = tid & 31;   // gather lane (32 lanes cover one 512B row)
    const int grp  = tid >> 5;   // gather group 0..7, owns rows grp*16..+15

    // stage this block's 2048 edge indices (coalesced int4)
    {
        const int4* s = (const int4*)(idx0 + (size_t)bm * (128 * DEG0));
        int4* d = (int4*)sIdx;
        d[tid]       = s[tid];
        d[tid + 256] = s[tid + 256];
    }
    __syncthreads();

    // phase 1: gather + mean; thread owns rows grp*16+i, cols lane*4..+3.
    // Result split to hi/lo bf16 kept in registers (64 VGPRs).
    ushort4 ah[16], al[16];
#pragma unroll
    for (int i = 0; i < 16; ++i) {
        const int rb = (grp * 16 + i) * DEG0;
        float4 a = make_float4(0.f, 0.f, 0.f, 0.f);
#pragma unroll
        for (int e = 0; e < DEG0; ++e) {
            const float4 v = x4[(size_t)sIdx[rb + e] * (D_IN / 4) + lane];
            a.x += v.x; a.y += v.y; a.z += v.z; a.w += v.w;
        }
        const float r = 1.0f / (float)DEG0;
        a.x *= r; a.y *= r; a.z *= r; a.w *= r;
        split4(a, ah[i], al[i]);
    }

    const int arow  = tid >> 1;  // A2 staging: 2 threads per row
    const int ahalf = tid & 1;

    for (int bn = 0; bn < 4; ++bn) {
        f32x4 acc[2][4];
#pragma unroll
        for (int mt = 0; mt < 2; ++mt)
#pragma unroll
            for (int nt = 0; nt < 4; ++nt) acc[mt][nt] = (f32x4)0.f;

#pragma unroll
        for (int kt = 0; kt < 8; ++kt) {
            const int k0 = kt * 32;
            // ---- stage A k-tile ----
            if (kt < 4) {
                // A1 (aggregated mean) from registers: cols kt*32..+31 live in
                // lanes with (lane>>3)==kt; each writes its 16 rows x 4 cols.
                if ((lane >> 3) == kt) {
                    const int c = (lane & 7) * 4;
#pragma unroll
                    for (int i = 0; i < 16; ++i) {
                        const int rr = grp * 16 + i;
                        *(ushort4*)&sA[0][rr][c] = ah[i];
                        *(ushort4*)&sA[1][rr][c] = al[i];
                    }
                }
            } else {
                // A2 = x[dst] fp32, convert during staging (L2-hot after bn=0)
                const float4* sx = x4 + (size_t)(bm * 128 + arow) * (D_IN / 4)
                                      + (kt - 4) * 8 + ahalf * 4;
#pragma unroll
                for (int q = 0; q < 4; ++q) {
                    ushort4 h, l;
                    split4(sx[q], h, l);
                    const int c = ahalf * 16 + q * 4;
                    *(ushort4*)&sA[0][arow][c] = h;
                    *(ushort4*)&sA[1][arow][c] = l;
                }
            }
            // ---- stage B k-tile (weights, L2-resident) ----
            {
                const int row = tid >> 2, seg = tid & 3;
                const unsigned short *Bh, *Bl; int koff;
                if (k0 < D_IN) { Bh = B1h; Bl = B1l; koff = k0; }
                else           { Bh = B2h; Bl = B2l; koff = k0 - D_IN; }
                const size_t g = (size_t)(bn * 64 + row) * D_IN + koff + seg * 8;
                *(uint4*)&sB[0][row][seg * 8] = *(const uint4*)(Bh + g);
                *(uint4*)&sB[1][row][seg * 8] = *(const uint4*)(Bl + g);
            }
            __syncthreads();

            bf16x8 Afh[2], Afl[2];
#pragma unroll
            for (int mt = 0; mt < 2; ++mt) {
                const int r = w * 32 + mt * 16 + l16;
                Afh[mt] = *(const bf16x8*)&sA[0][r][quad * 8];
                Afl[mt] = *(const bf16x8*)&sA[1][r][quad * 8];
            }
#pragma unroll
            for (int nt = 0; nt < 4; ++nt) {
                const int r = nt * 16 + l16;
                const bf16x8 Bfh = *(const bf16x8*)&sB[0][r][quad * 8];
                const bf16x8 Bfl = *(const bf16x8*)&sB[1][r][quad * 8];
#pragma unroll
                for (int mt = 0; mt < 2; ++mt) {
                    acc[mt][nt] = __builtin_amdgcn_mfma_f32_16x16x32_bf16(
                        Afl[mt], Bfh, acc[mt][nt], 0, 0, 0);
                    acc[mt][nt] = __builtin_amdgcn_mfma_f32_16x16x32_bf16(
                        Afh[mt], Bfl, acc[mt][nt], 0, 0, 0);
                    acc[mt][nt] = __builtin_amdgcn_mfma_f32_16x16x32_bf16(
                        Afh[mt], Bfh, acc[mt][nt], 0, 0, 0);
                }
            }
            __syncthreads();
        }

        // epilogue for this bn: D layout col=lane&15, row=quad*4+reg
#pragma unroll
        for (int mt = 0; mt < 2; ++mt) {
            const int row0 = bm * 128 + w * 32 + mt * 16 + quad * 4;
#pragma unroll
            for (int nt = 0; nt < 4; ++nt) {
                const int col = bn * 64 + nt * 16 + l16;
                const float bb = bias[col];
#pragma unroll
                for (int r = 0; r < 4; ++r) {
                    float v = gelu_exact(acc[mt][nt][r] + bb);
                    const unsigned short h = f2b(v);
                    Ch[(size_t)(row0 + r) * D_H + col] = h;
                    Cl[(size_t)(row0 + r) * D_H + col] = f2b(v - b2f(h));
                }
            }
        }
    }
}

extern "C" void kernel_launch(void* const* d_in, const int* in_sizes, int n_in,
                              void* d_out, int out_size, void* d_ws, size_t ws_size,
                              hipStream_t stream)
{
    const float* x        = (const float*)d_in[0];
    const int*   indices0 = (const int*)d_in[1];
    const int*   indices1 = (const int*)d_in[3];
    const float* Wl0 = (const float*)d_in[5];
    const float* bl0 = (const float*)d_in[6];
    const float* Wr0 = (const float*)d_in[7];
    const float* Wl1 = (const float*)d_in[8];
    const float* bl1 = (const float*)d_in[9];
    const float* Wr1 = (const float*)d_in[10];
    const float* Wo  = (const float*)d_in[11];
    const float* bo  = (const float*)d_in[12];
    float* out = (float*)d_out;

    // Workspace: hi/lo bf16 planes (ushort), then padded bo (float)
    unsigned short* p = (unsigned short*)d_ws;
    unsigned short* h0h  = p; p += (size_t)N1 * D_H;
    unsigned short* h0l  = p; p += (size_t)N1 * D_H;
    unsigned short* m1h  = p; p += (size_t)N2 * D_H;
    unsigned short* m1l  = p; p += (size_t)N2 * D_H;
    unsigned short* h1h  = p; p += (size_t)N2 * D_H;
    unsigned short* h1l  = p; p += (size_t)N2 * D_H;
    unsigned short* wl0h = p; p += 256 * 128;
    unsigned short* wl0l = p; p += 256 * 128;
    unsigned short* wr0h = p; p += 256 * 128;
    unsigned short* wr0l = p; p += 256 * 128;
    unsigned short* wl1h = p; p += 256 * 256;
    unsigned short* wl1l = p; p += 256 * 256;
    unsigned short* wr1h = p; p += 256 * 256;
    unsigned short* wr1l = p; p += 256 * 256;
    unsigned short* woh  = p; p += 64 * 256;
    unsigned short* wol  = p; p += 64 * 256;
    float* bo_pad = (float*)p;

    // --- all weight conversions in one launch ---
    prep_all<<<208, 256, 0, stream>>>(
        (const float4*)Wl0, (const float4*)Wr0, (const float4*)Wl1, (const float4*)Wr1,
        (const float4*)Wo, bo,
        (ushort4*)wl0h, (ushort4*)wl0l, (ushort4*)wr0h, (ushort4*)wr0l,
        (ushort4*)wl1h, (ushort4*)wl1l, (ushort4*)wr1h, (ushort4*)wr1l,
        (ushort4*)woh, (ushort4*)wol, bo_pad);

    // --- layer 0: fused gather + mean + GEMM + GELU ---
    l0_fused<<<N1 / 128, 256, 0, stream>>>(
        (const float4*)x, indices0, wl0h, wl0l, wr0h, wr0l, bl0, h0h, h0l);

    // --- layer 1 ---
    agg_split_bf16<DEG1, D_H / 4><<<N2 / (256 / (D_H / 4)), 256, 0, stream>>>(
        (const ushort4*)h0h, (const ushort4*)h0l, indices1, (ushort4*)m1h, (ushort4*)m1l, N2);

    gemm_mfma<D_H, D_H, true, true><<<dim3(N2 / 128, D_H / 64), 256, 0, stream>>>(
        m1h, m1l, h0h, h0l, wl1h, wl1l, wr1h, wr1l, bl1,
        nullptr, h1h, h1l, D_H, D_H);

    // --- final projection: N=64 padded, mask to 47 ---
    gemm_mfma<D_H, 0, false, false><<<dim3(N2 / 128, 1), 256, 0, stream>>>(
        h1h, h1l, h1h, h1l, woh, wol, woh, wol, bo_pad,
        out, nullptr, nullptr, D_OUT, D_OUT);
}